// Round 2
// baseline (230.406 us; speedup 1.0000x reference)
//
#include <hip/hip_runtime.h>
#include <math.h>

// Problem: B=16, N=2049, C=1024, w_qkv is (1024, 3072) row-major.
// out = softmax over n of  scale * (x[b,0,:] @ Wq) . (x[b,n+1,:] @ Wk)
// Reassociated: q_cls[b] = Wq^T x[b,0,:];  v[b] = Wk @ q_cls[b];
//               logit[b,n] = scale * x[b,n+1,:] . v[b]
// This version: 4 dispatches (was 5). A+A2 fused via intra-block 8-wave LDS
// reduce (8 cross-block partials instead of 64); K2 folds the 8-way partial
// sum into its staging loop; K3 stages v[b] in LDS. No cross-block atomics
// (the 3-dispatch atomic variant is parked until we know it wasn't the cause
// of the round-1 container failure).

#define BATCH 16
#define SEQ   2049
#define CH    1024
#define W3    3072
#define NOUT  2048
#define PD    8        // cross-block d-chunk partials

// ws layout (floats):
//   part   : [0, 8*16*1024) = 131072   (512 KB)
//   v      : [131072, +16384)
//   logits : [147456, +32768)

// ---------------- K1: q_cls partials, intra-block reduced ----------------
// grid (4 col-chunks x 8 d-chunks), block 512 (8 waves).
// Wave w: rows [pi*128 + w*16, +16), cols [ci*256 + lane*4, +4) (float4).
// 8-wave LDS reduce (2 phases of 8 batches) -> one partial per (pi,b,c).
// Wq read exactly once chip-wide (4 MB), coalesced 1 KB/row per wave.
__global__ __launch_bounds__(512) void qcls_part_kernel(
    const float* __restrict__ x, const float* __restrict__ w,
    float* __restrict__ part) {
    const int ci = blockIdx.x;         // 0..3
    const int pi = blockIdx.y;         // 0..7
    const int t  = threadIdx.x;
    const int lane = t & 63;
    const int wv   = t >> 6;           // 0..7

    __shared__ float  xs[BATCH][128];          // 8 KB
    __shared__ float4 red[8][8][64];           // 64 KB (8 waves x 8 batches)

    for (int i = t; i < BATCH * 128; i += 512) {
        const int b = i >> 7, dd = i & 127;
        xs[b][dd] = x[(size_t)b * SEQ * CH + pi * 128 + dd];
    }
    __syncthreads();

    const int c = ci * 256 + lane * 4;
    float4 acc[BATCH];
    #pragma unroll
    for (int b = 0; b < BATCH; ++b) acc[b] = {0.f, 0.f, 0.f, 0.f};

    const int drow0 = pi * 128 + wv * 16;
    #pragma unroll 4
    for (int dd = 0; dd < 16; ++dd) {
        const float4 wvec = *(const float4*)(w + (size_t)(drow0 + dd) * W3 + c);
        const int dl = wv * 16 + dd;
        #pragma unroll
        for (int b = 0; b < BATCH; ++b) {
            const float s = xs[b][dl];
            acc[b].x += s * wvec.x; acc[b].y += s * wvec.y;
            acc[b].z += s * wvec.z; acc[b].w += s * wvec.w;
        }
    }

    // 8-wave reduce, 2 phases of 8 batches each. Wave w owns batch p*8+w.
    #pragma unroll
    for (int p = 0; p < 2; ++p) {
        #pragma unroll
        for (int b2 = 0; b2 < 8; ++b2)
            red[wv][b2][lane] = acc[p * 8 + b2];
        __syncthreads();
        {
            const int b = p * 8 + wv;
            float4 s = red[0][wv][lane];
            #pragma unroll
            for (int ww = 1; ww < 8; ++ww) {
                const float4 r = red[ww][wv][lane];
                s.x += r.x; s.y += r.y; s.z += r.z; s.w += r.w;
            }
            *(float4*)(part + ((size_t)pi * BATCH + b) * CH + c) = s;
        }
        __syncthreads();
    }
}

// ---------------- K2: v[b,d] = Wk[d,:] . q_cls[b,:] ----------------
// grid 64, block 256 (4 waves, 4 d-rows each). Staging sums the 8 partials
// (512 KB from L2/L3 per block) into LDS -- the old reduce kernel, folded in.
__global__ __launch_bounds__(256) void v_kernel(
    const float* __restrict__ w, const float* __restrict__ part,
    float* __restrict__ v) {
    __shared__ float qs[BATCH * CH];   // 64 KB
    const int t = threadIdx.x;
    const float4* p4 = (const float4*)part;
    for (int i4 = t; i4 < BATCH * CH / 4; i4 += 256) {
        float4 s = p4[i4];
        #pragma unroll
        for (int p = 1; p < PD; ++p) {
            const float4 r = p4[p * (BATCH * CH / 4) + i4];
            s.x += r.x; s.y += r.y; s.z += r.z; s.w += r.w;
        }
        ((float4*)qs)[i4] = s;
    }
    __syncthreads();

    const int lane = t & 63;
    const int wave = t >> 6;
    #pragma unroll
    for (int k = 0; k < 4; ++k) {
        const int d = blockIdx.x * 16 + wave * 4 + k;
        const float* wrow = w + (size_t)d * W3 + CH;    // Wk = cols [1024,2048)
        float4 wv4[4];
        #pragma unroll
        for (int j = 0; j < 4; ++j)
            wv4[j] = *(const float4*)(wrow + lane * 4 + j * 256);
        #pragma unroll
        for (int b = 0; b < BATCH; ++b) {
            float acc = 0.f;
            #pragma unroll
            for (int j = 0; j < 4; ++j) {
                const float4 qv = *(const float4*)(&qs[b * CH + lane * 4 + j * 256]);
                acc += wv4[j].x * qv.x + wv4[j].y * qv.y
                     + wv4[j].z * qv.z + wv4[j].w * qv.w;
            }
            #pragma unroll
            for (int off = 32; off > 0; off >>= 1)
                acc += __shfl_down(acc, off, 64);
            if (lane == 0) v[b * CH + d] = acc;
        }
    }
}

// ---------------- K3: logits (the memory-bound streamer) ----------------
// One wave per (b,n) row: 1024-float dot with v[b]. grid 8192 x 256.
// All 4 rows of a block share one batch (2048 % 4 == 0) -> v[b] staged in LDS.
__global__ __launch_bounds__(256) void logits_kernel(
    const float* __restrict__ x, const float* __restrict__ v,
    float* __restrict__ logits) {
    const int t = threadIdx.x;
    const int lane = t & 63;
    const int row0 = blockIdx.x * 4;
    const int b = row0 >> 11;          // constant within block

    __shared__ float4 vs[CH / 4];      // 4 KB
    vs[t] = ((const float4*)(v + (size_t)b * CH))[t];
    __syncthreads();

    const int row = row0 + (t >> 6);
    const int n = row & (NOUT - 1);
    const float* xrow = x + ((size_t)b * SEQ + n + 1) * CH;
    float acc = 0.f;
    #pragma unroll
    for (int j = 0; j < 4; ++j) {
        const float4 xv = *(const float4*)(xrow + lane * 4 + j * 256);
        const float4 vv = vs[lane + j * 64];
        acc += xv.x * vv.x + xv.y * vv.y + xv.z * vv.z + xv.w * vv.w;
    }
    #pragma unroll
    for (int off = 32; off > 0; off >>= 1)
        acc += __shfl_down(acc, off, 64);
    if (lane == 0) logits[row] = acc * 0.03125f;   // scale = C^-0.5 = 1/32
}

// ---------------- K4: softmax over 2048 per batch ----------------
__global__ __launch_bounds__(256) void softmax_kernel(
    const float* __restrict__ logits, float* __restrict__ out) {
    const int b = blockIdx.x;
    const int t = threadIdx.x;
    __shared__ float sm[256];
    float val[8];
    float m = -1e30f;
    #pragma unroll
    for (int i = 0; i < 8; ++i) {
        val[i] = logits[b * NOUT + t + i * 256];
        m = fmaxf(m, val[i]);
    }
    sm[t] = m; __syncthreads();
    for (int s = 128; s > 0; s >>= 1) {
        if (t < s) sm[t] = fmaxf(sm[t], sm[t + s]);
        __syncthreads();
    }
    const float mx = sm[0];
    __syncthreads();
    float e[8];
    float sum = 0.f;
    #pragma unroll
    for (int i = 0; i < 8; ++i) { e[i] = expf(val[i] - mx); sum += e[i]; }
    sm[t] = sum; __syncthreads();
    for (int s = 128; s > 0; s >>= 1) {
        if (t < s) sm[t] += sm[t + s];
        __syncthreads();
    }
    const float inv = 1.0f / sm[0];
    #pragma unroll
    for (int i = 0; i < 8; ++i) out[b * NOUT + t + i * 256] = e[i] * inv;
}

extern "C" void kernel_launch(void* const* d_in, const int* in_sizes, int n_in,
                              void* d_out, int out_size, void* d_ws, size_t ws_size,
                              hipStream_t stream) {
    const float* x = (const float*)d_in[0];   // (16, 2049, 1024) fp32
    const float* w = (const float*)d_in[1];   // (1024, 3072) fp32
    float* out = (float*)d_out;               // (16, 2048) fp32
    float* ws = (float*)d_ws;

    float* part   = ws;                        // 131072 floats (512 KB)
    float* vbuf   = ws + 131072;               // 16384 floats
    float* logits = ws + 147456;               // 32768 floats

    qcls_part_kernel<<<dim3(4, 8), 512, 0, stream>>>(x, w, part);
    v_kernel<<<64, 256, 0, stream>>>(w, part, vbuf);
    logits_kernel<<<8192, 256, 0, stream>>>(x, vbuf, logits);
    softmax_kernel<<<BATCH, 256, 0, stream>>>(logits, out);
}